// Round 3
// baseline (979.748 us; speedup 1.0000x reference)
//
#include <hip/hip_runtime.h>

#define N_NODES 100000
#define F_IN 512
#define HID 16
#define CLS 7

#define BK_SHIFT 8
#define BK_NODES 256
#define NBK ((N_NODES + BK_NODES - 1) / BK_NODES)   // 391
#define BK_CAP 9216   // mean bucket = 8192 edges, sigma ~90; cap = +11 sigma

#define ADD4(a, v) { (a).x += (v).x; (a).y += (v).y; (a).z += (v).z; (a).w += (v).w; }
#define FMA4(acc, sc, wv) { (acc).x += (sc)*(wv).x; (acc).y += (sc)*(wv).y; (acc).z += (sc)*(wv).z; (acc).w += (sc)*(wv).w; }

// ---------------------------------------------------------------------------
// Edge-index dtype detection (int64 vs int32).
// ---------------------------------------------------------------------------
__global__ void detect_i64_kernel(const unsigned int* __restrict__ idx32,
                                  int* __restrict__ flag, int n_check) {
    __shared__ unsigned int s;
    if (threadIdx.x == 0) s = 0u;
    __syncthreads();
    unsigned int v = 0u;
    for (int i = threadIdx.x; i < n_check; i += blockDim.x)
        v |= idx32[2 * i + 1];
    atomicOr(&s, v);
    __syncthreads();
    if (threadIdx.x == 0) *flag = (s == 0u) ? 1 : 0;
}

// ---------------------------------------------------------------------------
// Single-pass multisplit into fixed-cap buckets (UNSORTED within bucket —
// downstream is order-insensitive LDS accumulation). Register-resident tile:
// read edges once, hist -> reserve -> scatter. Also counts per-node degree
// via global atomics (deg is 400KB, L2-resident).
// Edge packed to 4B: (dst&255)<<17 | src  (src < 2^17).
// ---------------------------------------------------------------------------
#define SB_T 512
#define SB_TILE 8192
#define SB_EPT (SB_TILE / SB_T)   // 16 edges per thread

__global__ __launch_bounds__(SB_T) void scatter_bin_kernel(const void* __restrict__ eidx,
                                                           long long E,
                                                           const int* __restrict__ flag,
                                                           int* __restrict__ cursor,
                                                           int* __restrict__ deg,
                                                           unsigned int* __restrict__ binned) {
    __shared__ int hist[NBK];
    __shared__ int gcur[NBK];
    const int is64 = *flag;
    const int tid = threadIdx.x;
    const long long tileBeg = (long long)blockIdx.x * SB_TILE;
    const bool evE = ((E & 1LL) == 0LL);

    for (int i = tid; i < NBK; i += SB_T) hist[i] = 0;
    __syncthreads();

    unsigned int vv[SB_EPT];
    int bb[SB_EPT];

#pragma unroll
    for (int j = 0; j < SB_EPT / 2; j++) {
        long long e = tileBeg + (long long)j * (2 * SB_T) + 2 * tid;
        int s0 = 0, d0 = 0, s1 = 0, d1 = 0;
        const bool ok0 = e < E, ok1 = (e + 1) < E;
        if (is64) {
            const long long* p = (const long long*)eidx;
            if (ok1 && evE) {
                longlong2 sp = *(const longlong2*)(p + e);
                longlong2 dp = *(const longlong2*)(p + E + e);
                s0 = (int)sp.x; s1 = (int)sp.y; d0 = (int)dp.x; d1 = (int)dp.y;
            } else {
                if (ok0) { s0 = (int)p[e];     d0 = (int)p[E + e]; }
                if (ok1) { s1 = (int)p[e + 1]; d1 = (int)p[E + e + 1]; }
            }
        } else {
            const int* p = (const int*)eidx;
            if (ok1 && evE) {
                int2 sp = *(const int2*)(p + e);
                int2 dp = *(const int2*)(p + E + e);
                s0 = sp.x; s1 = sp.y; d0 = dp.x; d1 = dp.y;
            } else {
                if (ok0) { s0 = p[e];     d0 = p[E + e]; }
                if (ok1) { s1 = p[e + 1]; d1 = p[E + e + 1]; }
            }
        }
        if (ok0) {
            int b = d0 >> BK_SHIFT;
            bb[2 * j] = b;
            vv[2 * j] = ((unsigned int)(d0 & (BK_NODES - 1)) << 17) | (unsigned int)s0;
            atomicAdd(&hist[b], 1);
            atomicAdd(&deg[d0], 1);
        } else bb[2 * j] = -1;
        if (ok1) {
            int b = d1 >> BK_SHIFT;
            bb[2 * j + 1] = b;
            vv[2 * j + 1] = ((unsigned int)(d1 & (BK_NODES - 1)) << 17) | (unsigned int)s1;
            atomicAdd(&hist[b], 1);
            atomicAdd(&deg[d1], 1);
        } else bb[2 * j + 1] = -1;
    }
    __syncthreads();
    for (int i = tid; i < NBK; i += SB_T)
        gcur[i] = hist[i] ? (i * BK_CAP + atomicAdd(&cursor[i], hist[i])) : 0;
    __syncthreads();
#pragma unroll
    for (int j = 0; j < SB_EPT; j++) {
        int b = bb[j];
        if (b >= 0) {
            int pos = atomicAdd(&gcur[b], 1);
            if (pos < (b + 1) * BK_CAP)              // overflow guard (unreachable)
                binned[pos] = vv[j];
        }
    }
}

// ---------------------------------------------------------------------------
// GEMM1: h1s[i][16] = (x[i][512] @ W1[512][16]) * rsqrt(deg[i]+1)
// 128 rows/block, 2 rows/thread, float4 LDS reads. HBM floor ~33us.
// ---------------------------------------------------------------------------
#define G1_ROWS 128
#define G1_KC 32
#define G1_LDX (G1_KC + 4)

__global__ __launch_bounds__(256) void gemm1_kernel(const float* __restrict__ x,
                                                    const float* __restrict__ W1,
                                                    const int* __restrict__ deg,
                                                    float* __restrict__ h1s) {
    __shared__ float Ws[F_IN * HID];             // 32 KB
    __shared__ float xs[G1_ROWS][G1_LDX];        // 18 KB
    const int tid = threadIdx.x;
    const int rowBase = blockIdx.x * G1_ROWS;

#pragma unroll
    for (int it = 0; it < 8; it++) {
        int f = it * 256 + tid;
        ((float4*)Ws)[f] = ((const float4*)W1)[f];
    }

    const int r  = tid >> 2;                     // 0..63
    const int j4 = tid & 3;
    float4 accA = make_float4(0.f, 0.f, 0.f, 0.f);
    float4 accB = make_float4(0.f, 0.f, 0.f, 0.f);
    const float4* Wf4 = (const float4*)Ws;

    for (int kc = 0; kc < F_IN; kc += G1_KC) {
        __syncthreads();
#pragma unroll
        for (int it = 0; it < 4; it++) {
            int f = it * 256 + tid;
            int row = f >> 3;
            int c4 = f & 7;
            int grow = rowBase + row;
            if (grow >= N_NODES) grow = N_NODES - 1;
            *((float4*)&xs[row][c4 * 4]) = ((const float4*)(x + (long long)grow * F_IN + kc))[c4];
        }
        __syncthreads();
#pragma unroll
        for (int k4 = 0; k4 < G1_KC / 4; k4++) {
            float4 xa = *(const float4*)&xs[r][k4 * 4];
            float4 xb = *(const float4*)&xs[r + 64][k4 * 4];
            int kb = (kc + k4 * 4) * 4 + j4;
            float4 w0 = Wf4[kb];
            float4 w1 = Wf4[kb + 4];
            float4 w2 = Wf4[kb + 8];
            float4 w3 = Wf4[kb + 12];
            FMA4(accA, xa.x, w0); FMA4(accA, xa.y, w1);
            FMA4(accA, xa.z, w2); FMA4(accA, xa.w, w3);
            FMA4(accB, xb.x, w0); FMA4(accB, xb.y, w1);
            FMA4(accB, xb.z, w2); FMA4(accB, xb.w, w3);
        }
    }
    int g0 = rowBase + r;
    if (g0 < N_NODES) {
        float dn = rsqrtf((float)(deg[g0] + 1));
        ((float4*)(h1s + (long long)g0 * HID))[j4] =
            make_float4(accA.x * dn, accA.y * dn, accA.z * dn, accA.w * dn);
    }
    int g1 = rowBase + 64 + r;
    if (g1 < N_NODES) {
        float dn = rsqrtf((float)(deg[g1] + 1));
        ((float4*)(h1s + (long long)g1 * HID))[j4] =
            make_float4(accB.x * dn, accB.y * dn, accB.z * dn, accB.w * dn);
    }
}

// ---------------------------------------------------------------------------
// Layer-1 aggregation, bucket-streamed: one block per 256-node bucket,
// unsorted packed edges -> LDS f32 atomics into acc[256][17] (pad 17 spreads
// banks: (dlo*17+c)&31). Divergence-free edge loop, 4 lanes x float4 per edge
// (one 64B h1s row per edge). Epilogue: bias+relu+GEMM2 -> h2s.
// ---------------------------------------------------------------------------
#define AGG1_T 512

__global__ __launch_bounds__(AGG1_T) void agg1_gemm2_kernel(const int* __restrict__ cursor,
                                                            const unsigned int* __restrict__ binned,
                                                            const int* __restrict__ deg,
                                                            const float* __restrict__ h1s,
                                                            const float* __restrict__ b1,
                                                            const float* __restrict__ W2,
                                                            float* __restrict__ h2s) {
    __shared__ float acc[BK_NODES][HID + 1];     // 17 KB
    __shared__ float W2s[HID][8];
    const int tid = threadIdx.x;
    const int b = blockIdx.x;
    const long long base = (long long)b * BK_CAP;
    int cnt = cursor[b];
    if (cnt > BK_CAP) cnt = BK_CAP;

    for (int i = tid; i < BK_NODES * (HID + 1); i += AGG1_T)
        ((float*)acc)[i] = 0.f;
    if (tid < HID * 8) {
        int j = tid >> 3, c = tid & 7;
        W2s[j][c] = (c < CLS) ? W2[j * CLS + c] : 0.f;
    }
    __syncthreads();

    const int es = tid >> 2;                     // 0..127
    const int j4 = tid & 3;
    const float4* h4 = (const float4*)h1s;
    int i = es;
    for (; i + 128 < cnt; i += 256) {            // 2-deep unroll for MLP
        unsigned int v0 = binned[base + i];
        unsigned int v1 = binned[base + i + 128];
        float4 g0 = h4[(long long)(v0 & 0x1FFFFu) * 4 + j4];
        float4 g1 = h4[(long long)(v1 & 0x1FFFFu) * 4 + j4];
        float* a0 = &acc[v0 >> 17][j4 * 4];
        float* a1 = &acc[v1 >> 17][j4 * 4];
        atomicAdd(a0 + 0, g0.x); atomicAdd(a0 + 1, g0.y);
        atomicAdd(a0 + 2, g0.z); atomicAdd(a0 + 3, g0.w);
        atomicAdd(a1 + 0, g1.x); atomicAdd(a1 + 1, g1.y);
        atomicAdd(a1 + 2, g1.z); atomicAdd(a1 + 3, g1.w);
    }
    for (; i < cnt; i += 128) {
        unsigned int v = binned[base + i];
        float4 g = h4[(long long)(v & 0x1FFFFu) * 4 + j4];
        float* ap = &acc[v >> 17][j4 * 4];
        atomicAdd(ap + 0, g.x); atomicAdd(ap + 1, g.y);
        atomicAdd(ap + 2, g.z); atomicAdd(ap + 3, g.w);
    }
    __syncthreads();

    // epilogue: 512 threads = 256 nodes x 2 halves (4 output cols each)
    const int ln = tid >> 1;
    const int half = tid & 1;
    const int n = b * BK_NODES + ln;
    if (n < N_NODES) {
        float dn = rsqrtf((float)(deg[n] + 1));
        const float* hs = h1s + (long long)n * HID;
        float t[HID];
#pragma unroll
        for (int j = 0; j < HID; j++)
            t[j] = fmaxf(b1[j] + dn * (acc[ln][j] + hs[j]), 0.f);
        float o0 = 0.f, o1 = 0.f, o2 = 0.f, o3 = 0.f;
#pragma unroll
        for (int j = 0; j < HID; j++) {
            float v = t[j];
            o0 += v * W2s[j][half * 4 + 0];
            o1 += v * W2s[j][half * 4 + 1];
            o2 += v * W2s[j][half * 4 + 2];
            o3 += v * W2s[j][half * 4 + 3];
        }
        ((float4*)(h2s + (long long)n * 8))[half] =
            make_float4(dn * o0, dn * o1, dn * o2, dn * o3);   // col7=0 via W2s pad
    }
}

// ---------------------------------------------------------------------------
// Layer-2 aggregation, bucket-streamed: 2 lanes x float4 per edge (32B h2s
// row), LDS f32 atomics into acc[256][9]. Epilogue writes final out (7 cols).
// ---------------------------------------------------------------------------
#define AGG2_T 512

__global__ __launch_bounds__(AGG2_T) void agg2_kernel(const int* __restrict__ cursor,
                                                      const unsigned int* __restrict__ binned,
                                                      const int* __restrict__ deg,
                                                      const float* __restrict__ h2s,
                                                      const float* __restrict__ b2,
                                                      float* __restrict__ out) {
    __shared__ float acc[BK_NODES][9];           // 9 KB
    const int tid = threadIdx.x;
    const int b = blockIdx.x;
    const long long base = (long long)b * BK_CAP;
    int cnt = cursor[b];
    if (cnt > BK_CAP) cnt = BK_CAP;

    for (int i = tid; i < BK_NODES * 9; i += AGG2_T)
        ((float*)acc)[i] = 0.f;
    __syncthreads();

    const int es = tid >> 1;                     // 0..255
    const int half = tid & 1;
    const float4* h4 = (const float4*)h2s;
    int i = es;
    for (; i + 256 < cnt; i += 512) {
        unsigned int v0 = binned[base + i];
        unsigned int v1 = binned[base + i + 256];
        float4 g0 = h4[(long long)(v0 & 0x1FFFFu) * 2 + half];
        float4 g1 = h4[(long long)(v1 & 0x1FFFFu) * 2 + half];
        float* a0 = &acc[v0 >> 17][half * 4];
        float* a1 = &acc[v1 >> 17][half * 4];
        atomicAdd(a0 + 0, g0.x); atomicAdd(a0 + 1, g0.y);
        atomicAdd(a0 + 2, g0.z); atomicAdd(a0 + 3, g0.w);
        atomicAdd(a1 + 0, g1.x); atomicAdd(a1 + 1, g1.y);
        atomicAdd(a1 + 2, g1.z); atomicAdd(a1 + 3, g1.w);
    }
    for (; i < cnt; i += 256) {
        unsigned int v = binned[base + i];
        float4 g = h4[(long long)(v & 0x1FFFFu) * 2 + half];
        float* ap = &acc[v >> 17][half * 4];
        atomicAdd(ap + 0, g.x); atomicAdd(ap + 1, g.y);
        atomicAdd(ap + 2, g.z); atomicAdd(ap + 3, g.w);
    }
    __syncthreads();

    const int ln = tid >> 1;
    const int n = b * BK_NODES + ln;
    if (n < N_NODES) {
        float dn = rsqrtf((float)(deg[n] + 1));
        float4 self = h4[(long long)n * 2 + half];
        const float* ap = &acc[ln][half * 4];
        long long ob = (long long)n * CLS + half * 4;
        if (half == 0) {
            out[ob + 0] = b2[0] + dn * (self.x + ap[0]);
            out[ob + 1] = b2[1] + dn * (self.y + ap[1]);
            out[ob + 2] = b2[2] + dn * (self.z + ap[2]);
            out[ob + 3] = b2[3] + dn * (self.w + ap[3]);
        } else {
            out[ob + 0] = b2[4] + dn * (self.x + ap[0]);
            out[ob + 1] = b2[5] + dn * (self.y + ap[1]);
            out[ob + 2] = b2[6] + dn * (self.z + ap[2]);
        }
    }
}

// ---------------------------------------------------------------------------
extern "C" void kernel_launch(void* const* d_in, const int* in_sizes, int n_in,
                              void* d_out, int out_size, void* d_ws, size_t ws_size,
                              hipStream_t stream) {
    const float* x    = (const float*)d_in[0];
    const void*  eidx = d_in[1];
    const float* W1   = (const float*)d_in[2];
    const float* b1   = (const float*)d_in[3];
    const float* W2   = (const float*)d_in[4];
    const float* b2   = (const float*)d_in[5];
    float* out = (float*)d_out;
    const long long E = (long long)in_sizes[1] / 2;

    // workspace carve-up (256B aligned); total ~25 MB
    char* ws = (char*)d_ws;
    size_t off = 0;
    auto alloc = [&](size_t bytes) -> void* {
        void* p = ws + off;
        off = (off + bytes + 255) & ~(size_t)255;
        return p;
    };
    int*          flag   = (int*)alloc(4);
    int*          cursor = (int*)alloc((size_t)NBK * 4);        // \ zeroed by one
    int*          deg    = (int*)alloc((size_t)N_NODES * 4);    // / memset below
    unsigned int* binned = (unsigned int*)alloc((size_t)NBK * BK_CAP * 4);
    float*        h1s    = (float*)alloc((size_t)N_NODES * HID * 4);
    float*        h2s    = (float*)alloc((size_t)N_NODES * 8 * 4);
    (void)ws_size;

    // one memset covers cursor + (alignment pad) + deg
    size_t zlen = (size_t)((char*)(deg + N_NODES) - (char*)cursor);
    hipMemsetAsync(cursor, 0, zlen, stream);

    detect_i64_kernel<<<1, 256, 0, stream>>>((const unsigned int*)eidx, flag,
                                             (int)(E < 4096 ? E : 4096));

    scatter_bin_kernel<<<(int)((E + SB_TILE - 1) / SB_TILE), SB_T, 0, stream>>>(
        eidx, E, flag, cursor, deg, binned);

    gemm1_kernel<<<(N_NODES + G1_ROWS - 1) / G1_ROWS, 256, 0, stream>>>(x, W1, deg, h1s);

    agg1_gemm2_kernel<<<NBK, AGG1_T, 0, stream>>>(cursor, binned, deg, h1s, b1, W2, h2s);

    agg2_kernel<<<NBK, AGG2_T, 0, stream>>>(cursor, binned, deg, h2s, b2, out);
}

// Round 4
// 657.289 us; speedup vs baseline: 1.4906x; 1.4906x over previous
//
#include <hip/hip_runtime.h>

#define N_NODES 100000
#define F_IN 512
#define HID 16
#define CLS 7

#define ADD4(a, v) { (a).x += (v).x; (a).y += (v).y; (a).z += (v).z; (a).w += (v).w; }
#define FMA4(acc, sc, wv) { (acc).x += (sc)*(wv).x; (acc).y += (sc)*(wv).y; (acc).z += (sc)*(wv).z; (acc).w += (sc)*(wv).w; }

// ---------------------------------------------------------------------------
// Edge-index dtype detection (int64 vs int32).
// ---------------------------------------------------------------------------
__global__ void detect_i64_kernel(const unsigned int* __restrict__ idx32,
                                  int* __restrict__ flag, int n_check) {
    __shared__ unsigned int s;
    if (threadIdx.x == 0) s = 0u;
    __syncthreads();
    unsigned int v = 0u;
    for (int i = threadIdx.x; i < n_check; i += blockDim.x)
        v |= idx32[2 * i + 1];
    atomicOr(&s, v);
    __syncthreads();
    if (threadIdx.x == 0) *flag = (s == 0u) ? 1 : 0;
}

// ---------------------------------------------------------------------------
// Node-direct scatter: pos = atomicAdd(&cnt[dst]); nbr[dst*cap+pos] = src.
// No LDS, no sort, no csr_build kernel. cnt doubles as the degree array.
// 3.2M atomics hit a 400KB L2-resident array; scattered 4B writes are
// L2-write-combined. Downstream aggregation stays node-parallel.
// ---------------------------------------------------------------------------
#define SC_T 256
#define SC_EPT 8   // edges per thread (4 vectorized pairs)

__global__ __launch_bounds__(SC_T) void scatter_node_kernel(const void* __restrict__ eidx,
                                                            long long E,
                                                            const int* __restrict__ flag,
                                                            int* __restrict__ cnt,
                                                            int* __restrict__ nbr,
                                                            int cap) {
    const int is64 = *flag;
    const int tid = threadIdx.x;
    const long long tileBeg = (long long)blockIdx.x * (SC_T * SC_EPT);
    const bool evE = ((E & 1LL) == 0LL);

#pragma unroll
    for (int j = 0; j < SC_EPT / 2; j++) {
        long long e = tileBeg + (long long)j * (2 * SC_T) + 2 * tid;
        int s0 = 0, d0 = 0, s1 = 0, d1 = 0;
        const bool ok0 = e < E, ok1 = (e + 1) < E;
        if (is64) {
            const long long* p = (const long long*)eidx;
            if (ok1 && evE) {
                longlong2 sp = *(const longlong2*)(p + e);
                longlong2 dp = *(const longlong2*)(p + E + e);
                s0 = (int)sp.x; s1 = (int)sp.y; d0 = (int)dp.x; d1 = (int)dp.y;
            } else {
                if (ok0) { s0 = (int)p[e];     d0 = (int)p[E + e]; }
                if (ok1) { s1 = (int)p[e + 1]; d1 = (int)p[E + e + 1]; }
            }
        } else {
            const int* p = (const int*)eidx;
            if (ok1 && evE) {
                int2 sp = *(const int2*)(p + e);
                int2 dp = *(const int2*)(p + E + e);
                s0 = sp.x; s1 = sp.y; d0 = dp.x; d1 = dp.y;
            } else {
                if (ok0) { s0 = p[e];     d0 = p[E + e]; }
                if (ok1) { s1 = p[e + 1]; d1 = p[E + e + 1]; }
            }
        }
        if (ok0) {
            int pos = atomicAdd(&cnt[d0], 1);
            if (pos < cap) nbr[d0 * cap + pos] = s0;   // overflow guard (unreachable)
        }
        if (ok1) {
            int pos = atomicAdd(&cnt[d1], 1);
            if (pos < cap) nbr[d1 * cap + pos] = s1;
        }
    }
}

// ---------------------------------------------------------------------------
// GEMM1: h1s[i][16] = (x[i][512] @ W1[512][16]) * rsqrt(deg[i]+1)
// 128 rows/block, 2 rows/thread, float4 LDS reads. HBM floor ~33us.
// ---------------------------------------------------------------------------
#define G1_ROWS 128
#define G1_KC 32
#define G1_LDX (G1_KC + 4)

__global__ __launch_bounds__(256) void gemm1_kernel(const float* __restrict__ x,
                                                    const float* __restrict__ W1,
                                                    const int* __restrict__ cnt,
                                                    float* __restrict__ h1s) {
    __shared__ float Ws[F_IN * HID];             // 32 KB
    __shared__ float xs[G1_ROWS][G1_LDX];        // 18 KB
    const int tid = threadIdx.x;
    const int rowBase = blockIdx.x * G1_ROWS;

#pragma unroll
    for (int it = 0; it < 8; it++) {
        int f = it * 256 + tid;
        ((float4*)Ws)[f] = ((const float4*)W1)[f];
    }

    const int r  = tid >> 2;                     // 0..63
    const int j4 = tid & 3;
    float4 accA = make_float4(0.f, 0.f, 0.f, 0.f);
    float4 accB = make_float4(0.f, 0.f, 0.f, 0.f);
    const float4* Wf4 = (const float4*)Ws;

    for (int kc = 0; kc < F_IN; kc += G1_KC) {
        __syncthreads();
#pragma unroll
        for (int it = 0; it < 4; it++) {
            int f = it * 256 + tid;
            int row = f >> 3;
            int c4 = f & 7;
            int grow = rowBase + row;
            if (grow >= N_NODES) grow = N_NODES - 1;
            *((float4*)&xs[row][c4 * 4]) = ((const float4*)(x + (long long)grow * F_IN + kc))[c4];
        }
        __syncthreads();
#pragma unroll
        for (int k4 = 0; k4 < G1_KC / 4; k4++) {
            float4 xa = *(const float4*)&xs[r][k4 * 4];
            float4 xb = *(const float4*)&xs[r + 64][k4 * 4];
            int kb = (kc + k4 * 4) * 4 + j4;
            float4 w0 = Wf4[kb];
            float4 w1 = Wf4[kb + 4];
            float4 w2 = Wf4[kb + 8];
            float4 w3 = Wf4[kb + 12];
            FMA4(accA, xa.x, w0); FMA4(accA, xa.y, w1);
            FMA4(accA, xa.z, w2); FMA4(accA, xa.w, w3);
            FMA4(accB, xb.x, w0); FMA4(accB, xb.y, w1);
            FMA4(accB, xb.z, w2); FMA4(accB, xb.w, w3);
        }
    }
    int g0 = rowBase + r;
    if (g0 < N_NODES) {
        float dn = rsqrtf((float)(cnt[g0] + 1));
        ((float4*)(h1s + (long long)g0 * HID))[j4] =
            make_float4(accA.x * dn, accA.y * dn, accA.z * dn, accA.w * dn);
    }
    int g1 = rowBase + 64 + r;
    if (g1 < N_NODES) {
        float dn = rsqrtf((float)(cnt[g1] + 1));
        ((float4*)(h1s + (long long)g1 * HID))[j4] =
            make_float4(accB.x * dn, accB.y * dn, accB.z * dn, accB.w * dn);
    }
}

// ---------------------------------------------------------------------------
// Fused layer-1 gather (int4 index loads, unroll 8, 4 accumulators) + bias +
// relu + GEMM2. 4 lanes per node; 64 nodes per 256-thread block. Node-parallel
// (proven latency-hiding) with implicit rowptr = n*cap.
// ---------------------------------------------------------------------------
#define A1_NODES 64

__global__ __launch_bounds__(256) void agg1_gemm2_kernel(const int* __restrict__ cnt,
                                                         const int* __restrict__ nbr,
                                                         int cap,
                                                         const float* __restrict__ h1s,
                                                         const float* __restrict__ b1,
                                                         const float* __restrict__ W2,
                                                         float* __restrict__ h2s) {
    __shared__ float W2s[HID][8];
    __shared__ float t_lds[A1_NODES][HID + 1];
    const int tid = threadIdx.x;
    if (tid < HID * 8) {
        int j = tid >> 3, c = tid & 7;
        W2s[j][c] = (c < CLS) ? W2[j * CLS + c] : 0.f;
    }
    const int ln = tid >> 2;
    const int j4 = tid & 3;
    const int n = blockIdx.x * A1_NODES + ln;
    float dn = 0.f;
    if (n < N_NODES) {
        int deg = cnt[n];
        if (deg > cap) deg = cap;
        const int beg = n * cap;                 // cap%4==0 -> 16B-aligned
        const int end = beg + deg;
        const float4* h4 = (const float4*)h1s;
        float4 a0 = make_float4(0.f, 0.f, 0.f, 0.f);
        float4 a1 = make_float4(0.f, 0.f, 0.f, 0.f);
        float4 a2 = make_float4(0.f, 0.f, 0.f, 0.f);
        float4 a3 = make_float4(0.f, 0.f, 0.f, 0.f);
        int k = beg;
        for (; k + 8 <= end; k += 8) {
            int4 s0 = *(const int4*)(nbr + k);
            int4 s1 = *(const int4*)(nbr + k + 4);
            float4 v0 = h4[(long long)s0.x * 4 + j4];
            float4 v1 = h4[(long long)s0.y * 4 + j4];
            float4 v2 = h4[(long long)s0.z * 4 + j4];
            float4 v3 = h4[(long long)s0.w * 4 + j4];
            float4 v4 = h4[(long long)s1.x * 4 + j4];
            float4 v5 = h4[(long long)s1.y * 4 + j4];
            float4 v6 = h4[(long long)s1.z * 4 + j4];
            float4 v7 = h4[(long long)s1.w * 4 + j4];
            ADD4(a0, v0); ADD4(a1, v1); ADD4(a2, v2); ADD4(a3, v3);
            ADD4(a0, v4); ADD4(a1, v5); ADD4(a2, v6); ADD4(a3, v7);
        }
        if (k + 4 <= end) {
            int4 s0 = *(const int4*)(nbr + k);
            float4 v0 = h4[(long long)s0.x * 4 + j4];
            float4 v1 = h4[(long long)s0.y * 4 + j4];
            float4 v2 = h4[(long long)s0.z * 4 + j4];
            float4 v3 = h4[(long long)s0.w * 4 + j4];
            ADD4(a0, v0); ADD4(a1, v1); ADD4(a2, v2); ADD4(a3, v3);
            k += 4;
        }
        for (; k < end; k++) {
            float4 v = h4[(long long)nbr[k] * 4 + j4];
            ADD4(a0, v);
        }
        dn = rsqrtf((float)(deg + 1));
        float4 self = h4[(long long)n * 4 + j4];
        float4 bb = ((const float4*)b1)[j4];
        float* tp = &t_lds[ln][j4 * 4];
        tp[0] = fmaxf(bb.x + dn * (a0.x + a1.x + a2.x + a3.x + self.x), 0.f);
        tp[1] = fmaxf(bb.y + dn * (a0.y + a1.y + a2.y + a3.y + self.y), 0.f);
        tp[2] = fmaxf(bb.z + dn * (a0.z + a1.z + a2.z + a3.z + self.z), 0.f);
        tp[3] = fmaxf(bb.w + dn * (a0.w + a1.w + a2.w + a3.w + self.w), 0.f);
    }
    __syncthreads();
    if (n < N_NODES) {
        float b0 = 0.f, c1 = 0.f;
#pragma unroll
        for (int j = 0; j < HID; j++) {
            float v = t_lds[ln][j];
            b0 += v * W2s[j][2 * j4];
            c1 += v * W2s[j][2 * j4 + 1];
        }
        h2s[(long long)n * 8 + 2 * j4]     = dn * b0;   // col7 = 0 via W2s pad
        h2s[(long long)n * 8 + 2 * j4 + 1] = dn * c1;
    }
}

// ---------------------------------------------------------------------------
// Layer-2 gather: 2 lanes/node, float4 gathers, int4 index loads, unroll 8.
// 128 nodes/block, node-parallel with implicit rowptr = n*cap.
// ---------------------------------------------------------------------------
#define A2_NODES 128

__global__ __launch_bounds__(256) void agg2_gather_kernel(const int* __restrict__ cnt,
                                                          const int* __restrict__ nbr,
                                                          int cap,
                                                          const float* __restrict__ h2s,
                                                          const float* __restrict__ b2,
                                                          float* __restrict__ out) {
    const int tid = threadIdx.x;
    const int ln = tid >> 1;
    const int half = tid & 1;
    const int n = blockIdx.x * A2_NODES + ln;
    if (n >= N_NODES) return;
    int deg = cnt[n];
    if (deg > cap) deg = cap;
    const int beg = n * cap;
    const int end = beg + deg;
    const float4* h4 = (const float4*)h2s;       // node row = 2 float4
    float4 a0 = make_float4(0.f, 0.f, 0.f, 0.f);
    float4 a1 = make_float4(0.f, 0.f, 0.f, 0.f);
    float4 a2 = make_float4(0.f, 0.f, 0.f, 0.f);
    float4 a3 = make_float4(0.f, 0.f, 0.f, 0.f);
    int k = beg;
    for (; k + 8 <= end; k += 8) {
        int4 s0 = *(const int4*)(nbr + k);
        int4 s1 = *(const int4*)(nbr + k + 4);
        float4 v0 = h4[(long long)s0.x * 2 + half];
        float4 v1 = h4[(long long)s0.y * 2 + half];
        float4 v2 = h4[(long long)s0.z * 2 + half];
        float4 v3 = h4[(long long)s0.w * 2 + half];
        float4 v4 = h4[(long long)s1.x * 2 + half];
        float4 v5 = h4[(long long)s1.y * 2 + half];
        float4 v6 = h4[(long long)s1.z * 2 + half];
        float4 v7 = h4[(long long)s1.w * 2 + half];
        ADD4(a0, v0); ADD4(a1, v1); ADD4(a2, v2); ADD4(a3, v3);
        ADD4(a0, v4); ADD4(a1, v5); ADD4(a2, v6); ADD4(a3, v7);
    }
    if (k + 4 <= end) {
        int4 s0 = *(const int4*)(nbr + k);
        float4 v0 = h4[(long long)s0.x * 2 + half];
        float4 v1 = h4[(long long)s0.y * 2 + half];
        float4 v2 = h4[(long long)s0.z * 2 + half];
        float4 v3 = h4[(long long)s0.w * 2 + half];
        ADD4(a0, v0); ADD4(a1, v1); ADD4(a2, v2); ADD4(a3, v3);
        k += 4;
    }
    for (; k < end; k++) {
        float4 v = h4[(long long)nbr[k] * 2 + half];
        ADD4(a0, v);
    }
    float dn = rsqrtf((float)(deg + 1));
    float4 self = h4[(long long)n * 2 + half];
    float tx = self.x + a0.x + a1.x + a2.x + a3.x;
    float ty = self.y + a0.y + a1.y + a2.y + a3.y;
    float tz = self.z + a0.z + a1.z + a2.z + a3.z;
    float tw = self.w + a0.w + a1.w + a2.w + a3.w;
    long long ob = (long long)n * CLS;
    if (half == 0) {
        out[ob + 0] = b2[0] + dn * tx;
        out[ob + 1] = b2[1] + dn * ty;
        out[ob + 2] = b2[2] + dn * tz;
        out[ob + 3] = b2[3] + dn * tw;
    } else {
        out[ob + 4] = b2[4] + dn * tx;
        out[ob + 5] = b2[5] + dn * ty;
        out[ob + 6] = b2[6] + dn * tz;
    }
}

// ---------------------------------------------------------------------------
extern "C" void kernel_launch(void* const* d_in, const int* in_sizes, int n_in,
                              void* d_out, int out_size, void* d_ws, size_t ws_size,
                              hipStream_t stream) {
    const float* x    = (const float*)d_in[0];
    const void*  eidx = d_in[1];
    const float* W1   = (const float*)d_in[2];
    const float* b1   = (const float*)d_in[3];
    const float* W2   = (const float*)d_in[4];
    const float* b2   = (const float*)d_in[5];
    float* out = (float*)d_out;
    const long long E = (long long)in_sizes[1] / 2;

    // workspace carve-up (256B aligned)
    char* ws = (char*)d_ws;
    size_t off = 0;
    auto alloc = [&](size_t bytes) -> void* {
        void* p = ws + off;
        off = (off + bytes + 255) & ~(size_t)255;
        return p;
    };
    int*   flag = (int*)alloc(4);
    int*   cnt  = (int*)alloc((size_t)N_NODES * 4);
    float* h1s  = (float*)alloc((size_t)N_NODES * HID * 4);
    float* h2s  = (float*)alloc((size_t)N_NODES * 8 * 4);
    // nbr gets the rest; prefer cap=96 (mean deg 32 + 11 sigma), degrade if tight
    size_t avail = (ws_size > off) ? (ws_size - off) : 0;
    int cap = (int)(avail / ((size_t)N_NODES * 4));
    if (cap > 96) cap = 96;
    cap &= ~7;                                   // multiple of 8 (16B-aligned rows)
    if (cap < 64) cap = 64;                      // floor; P(deg>64) ~ 3e-7/node
    int* nbr = (int*)alloc((size_t)N_NODES * cap * 4);
    (void)ws_size;

    hipMemsetAsync(cnt, 0, (size_t)N_NODES * 4, stream);

    detect_i64_kernel<<<1, 256, 0, stream>>>((const unsigned int*)eidx, flag,
                                             (int)(E < 4096 ? E : 4096));

    scatter_node_kernel<<<(int)((E + SC_T * SC_EPT - 1) / (SC_T * SC_EPT)), SC_T, 0, stream>>>(
        eidx, E, flag, cnt, nbr, cap);

    gemm1_kernel<<<(N_NODES + G1_ROWS - 1) / G1_ROWS, 256, 0, stream>>>(x, W1, cnt, h1s);

    agg1_gemm2_kernel<<<(N_NODES + A1_NODES - 1) / A1_NODES, 256, 0, stream>>>(
        cnt, nbr, cap, h1s, b1, W2, h2s);

    agg2_gather_kernel<<<(N_NODES + A2_NODES - 1) / A2_NODES, 256, 0, stream>>>(
        cnt, nbr, cap, h2s, b2, out);
}

// Round 5
// 440.009 us; speedup vs baseline: 2.2267x; 1.4938x over previous
//
#include <hip/hip_runtime.h>

#define N_NODES 100000
#define F_IN 512
#define HID 16
#define CLS 7

#define BK_SHIFT 8
#define BK_NODES 256
#define NBK ((N_NODES + BK_NODES - 1) / BK_NODES)   // 391
#define BK_CAP 9216   // mean bucket = 8192 edges; cap = +11 sigma

#define SB_TILE 4096
#define SB_EPT 16          // edges per thread (256 threads)

#define G1_ROWS 128
#define G1_KC 32
#define G1_LDX (G1_KC + 4)

#define ADD4(a, v) { (a).x += (v).x; (a).y += (v).y; (a).z += (v).z; (a).w += (v).w; }
#define FMA4(acc, sc, wv) { (acc).x += (sc)*(wv).x; (acc).y += (sc)*(wv).y; (acc).z += (sc)*(wv).z; (acc).w += (sc)*(wv).w; }

// ---------------------------------------------------------------------------
// FAT kernel: blocks [0, scBlocks) = edge multisplit into fixed-cap buckets
// (R2-proven: reg tile, LDS hist -> global reserve -> scatter, coalesced-ish
// runs); blocks [scBlocks, ...) = gemm1 x@W1 -> h1s UNSCALED (dinv applied
// later in csr_build). The two halves are independent -> true overlap of
// a latency-bound phase with a compute/LDS-bound phase in ONE dispatch.
// Per-block dtype detect: OR hi-dwords of own tile's src half (int64 view of
// src half is always in-bounds; int32 data makes it nonzero w.p. ~1).
// Edge packed to 4B: (dst&255)<<17 | src  (src < 2^17).
// ---------------------------------------------------------------------------
__global__ __launch_bounds__(256) void fat_kernel(const void* __restrict__ eidx,
                                                  long long E,
                                                  int* __restrict__ cursor,
                                                  unsigned int* __restrict__ binned,
                                                  const float* __restrict__ x,
                                                  const float* __restrict__ W1,
                                                  float* __restrict__ h1s,
                                                  int scBlocks) {
    __shared__ float Ws[F_IN * HID];             // 32 KB (gemm)
    __shared__ float xs[G1_ROWS][G1_LDX];        // 18 KB (gemm)
    __shared__ int hist[NBK];                    // (scatter)
    __shared__ int gcur[NBK];                    // (scatter)
    __shared__ unsigned int det;                 // (scatter)
    const int tid = threadIdx.x;

    if ((int)blockIdx.x < scBlocks) {
        // ----------------- scatter part -----------------
        const long long tileBeg = (long long)blockIdx.x * SB_TILE;
        long long remll = E - tileBeg;
        const int tcnt = (int)(remll < SB_TILE ? remll : SB_TILE);
        const bool evE = ((E & 1LL) == 0LL);

        for (int i = tid; i < NBK; i += 256) hist[i] = 0;
        if (tid == 0) det = 0u;
        __syncthreads();

        {   // local dtype detect on own tile (src half only -> in bounds)
            unsigned int myor = 0u;
            const unsigned long long* p64 = (const unsigned long long*)eidx;
            for (int i = tid; i < tcnt; i += 256)
                myor |= (unsigned int)(p64[tileBeg + i] >> 32);
            if (myor) atomicOr(&det, 1u);
        }
        __syncthreads();
        const int is64 = (det == 0u) ? 1 : 0;

        unsigned int vv[SB_EPT];
        int bb[SB_EPT];

#pragma unroll
        for (int j = 0; j < SB_EPT / 2; j++) {
            long long e = tileBeg + (long long)j * 512 + 2 * tid;
            int s0 = 0, d0 = 0, s1 = 0, d1 = 0;
            const bool ok0 = e < E, ok1 = (e + 1) < E;
            if (is64) {
                const long long* p = (const long long*)eidx;
                if (ok1 && evE) {
                    longlong2 sp = *(const longlong2*)(p + e);
                    longlong2 dp = *(const longlong2*)(p + E + e);
                    s0 = (int)sp.x; s1 = (int)sp.y; d0 = (int)dp.x; d1 = (int)dp.y;
                } else {
                    if (ok0) { s0 = (int)p[e];     d0 = (int)p[E + e]; }
                    if (ok1) { s1 = (int)p[e + 1]; d1 = (int)p[E + e + 1]; }
                }
            } else {
                const int* p = (const int*)eidx;
                if (ok1 && evE) {
                    int2 sp = *(const int2*)(p + e);
                    int2 dp = *(const int2*)(p + E + e);
                    s0 = sp.x; s1 = sp.y; d0 = dp.x; d1 = dp.y;
                } else {
                    if (ok0) { s0 = p[e];     d0 = p[E + e]; }
                    if (ok1) { s1 = p[e + 1]; d1 = p[E + e + 1]; }
                }
            }
            if (ok0) {
                int b = d0 >> BK_SHIFT;
                bb[2 * j] = b;
                vv[2 * j] = ((unsigned int)(d0 & (BK_NODES - 1)) << 17) | (unsigned int)s0;
                atomicAdd(&hist[b], 1);
            } else bb[2 * j] = -1;
            if (ok1) {
                int b = d1 >> BK_SHIFT;
                bb[2 * j + 1] = b;
                vv[2 * j + 1] = ((unsigned int)(d1 & (BK_NODES - 1)) << 17) | (unsigned int)s1;
                atomicAdd(&hist[b], 1);
            } else bb[2 * j + 1] = -1;
        }
        __syncthreads();
        for (int i = tid; i < NBK; i += 256)
            gcur[i] = hist[i] ? (i * BK_CAP + atomicAdd(&cursor[i], hist[i])) : 0;
        __syncthreads();
#pragma unroll
        for (int j = 0; j < SB_EPT; j++) {
            int b = bb[j];
            if (b >= 0) {
                int pos = atomicAdd(&gcur[b], 1);
                if (pos < (b + 1) * BK_CAP)          // overflow guard (unreachable)
                    binned[pos] = vv[j];
            }
        }
    } else {
        // ----------------- gemm part: h1s = x @ W1 (unscaled) -----------------
        const int rowBase = ((int)blockIdx.x - scBlocks) * G1_ROWS;

#pragma unroll
        for (int it = 0; it < 8; it++) {
            int f = it * 256 + tid;
            ((float4*)Ws)[f] = ((const float4*)W1)[f];
        }

        const int r  = tid >> 2;                 // 0..63
        const int j4 = tid & 3;
        float4 accA = make_float4(0.f, 0.f, 0.f, 0.f);
        float4 accB = make_float4(0.f, 0.f, 0.f, 0.f);
        const float4* Wf4 = (const float4*)Ws;

        for (int kc = 0; kc < F_IN; kc += G1_KC) {
            __syncthreads();
#pragma unroll
            for (int it = 0; it < 4; it++) {
                int f = it * 256 + tid;
                int row = f >> 3;
                int c4 = f & 7;
                int grow = rowBase + row;
                if (grow >= N_NODES) grow = N_NODES - 1;
                *((float4*)&xs[row][c4 * 4]) = ((const float4*)(x + (long long)grow * F_IN + kc))[c4];
            }
            __syncthreads();
#pragma unroll
            for (int k4 = 0; k4 < G1_KC / 4; k4++) {
                float4 xa = *(const float4*)&xs[r][k4 * 4];
                float4 xb = *(const float4*)&xs[r + 64][k4 * 4];
                int kb = (kc + k4 * 4) * 4 + j4;
                float4 w0 = Wf4[kb];
                float4 w1 = Wf4[kb + 4];
                float4 w2 = Wf4[kb + 8];
                float4 w3 = Wf4[kb + 12];
                FMA4(accA, xa.x, w0); FMA4(accA, xa.y, w1);
                FMA4(accA, xa.z, w2); FMA4(accA, xa.w, w3);
                FMA4(accB, xb.x, w0); FMA4(accB, xb.y, w1);
                FMA4(accB, xb.z, w2); FMA4(accB, xb.w, w3);
            }
        }
        int g0 = rowBase + r;
        if (g0 < N_NODES)
            ((float4*)(h1s + (long long)g0 * HID))[j4] = accA;
        int g1 = rowBase + 64 + r;
        if (g1 < N_NODES)
            ((float4*)(h1s + (long long)g1 * HID))[j4] = accB;
    }
}

// ---------------------------------------------------------------------------
// Per-bucket CSR finalize (R2-proven) + NEW epilogue: scale this bucket's
// h1s rows by dinv (gemm wrote them unscaled; same multiply, bit-identical).
// ---------------------------------------------------------------------------
__global__ __launch_bounds__(512) void csr_build_kernel(const int* __restrict__ cursor,
                                                        unsigned int* __restrict__ binned,
                                                        float* __restrict__ dinv,
                                                        int* __restrict__ rowptr,
                                                        int* __restrict__ degA,
                                                        float* __restrict__ h1s) {
    __shared__ unsigned int stage[BK_CAP];       // 36 KB
    __shared__ int hist[BK_NODES];
    __shared__ int scanv[BK_NODES];
    __shared__ int curs[BK_NODES];
    const int tid = threadIdx.x;
    const int b = blockIdx.x;
    const int base = b * BK_CAP;
    int cnt = cursor[b];
    if (cnt > BK_CAP) cnt = BK_CAP;
    if (tid < BK_NODES) hist[tid] = 0;
    __syncthreads();
    const int cnt4 = cnt >> 2;
    for (int i = tid; i < cnt4; i += 512) {
        uint4 u = ((const uint4*)(binned + base))[i];
        ((uint4*)stage)[i] = u;
        atomicAdd(&hist[u.x >> 17], 1);
        atomicAdd(&hist[u.y >> 17], 1);
        atomicAdd(&hist[u.z >> 17], 1);
        atomicAdd(&hist[u.w >> 17], 1);
    }
    for (int i = (cnt4 << 2) + tid; i < cnt; i += 512) {
        unsigned int u = binned[base + i];
        stage[i] = u;
        atomicAdd(&hist[u >> 17], 1);
    }
    __syncthreads();
    if (tid < BK_NODES) scanv[tid] = hist[tid];
    __syncthreads();
    for (int off = 1; off < BK_NODES; off <<= 1) {
        int a = 0;
        if (tid < BK_NODES && tid >= off) a = scanv[tid - off];
        __syncthreads();
        if (tid < BK_NODES) scanv[tid] += a;
        __syncthreads();
    }
    if (tid < BK_NODES) {
        int e = scanv[tid] - hist[tid];
        curs[tid] = e;
        int g = b * BK_NODES + tid;
        if (g < N_NODES) {
            rowptr[g] = base + e;
            degA[g] = hist[tid];
            dinv[g] = rsqrtf((float)(hist[tid] + 1));   // +1 self-loop
        }
    }
    __syncthreads();
    for (int i = tid; i < cnt4; i += 512) {
        uint4 u = ((const uint4*)stage)[i];
        int p0 = atomicAdd(&curs[(int)(u.x >> 17)], 1); binned[base + p0] = u.x & 0x1FFFFu;
        int p1 = atomicAdd(&curs[(int)(u.y >> 17)], 1); binned[base + p1] = u.y & 0x1FFFFu;
        int p2 = atomicAdd(&curs[(int)(u.z >> 17)], 1); binned[base + p2] = u.z & 0x1FFFFu;
        int p3 = atomicAdd(&curs[(int)(u.w >> 17)], 1); binned[base + p3] = u.w & 0x1FFFFu;
    }
    for (int i = (cnt4 << 2) + tid; i < cnt; i += 512) {
        unsigned int u = stage[i];
        int p = atomicAdd(&curs[(int)(u >> 17)], 1);
        binned[base + p] = u & 0x1FFFFu;             // in place: binned becomes csr_src
    }
    // ---- h1 scale epilogue: 2 threads/node x 2 float4 (hist stable since scan)
    {
        const int ln = tid >> 1;                 // 0..255
        const int hf = tid & 1;
        const int g = b * BK_NODES + ln;
        if (g < N_NODES) {
            float dn = rsqrtf((float)(hist[ln] + 1));
            float4* hp = (float4*)(h1s + (long long)g * HID);
            float4 v0 = hp[hf * 2];
            float4 v1 = hp[hf * 2 + 1];
            hp[hf * 2]     = make_float4(v0.x * dn, v0.y * dn, v0.z * dn, v0.w * dn);
            hp[hf * 2 + 1] = make_float4(v1.x * dn, v1.y * dn, v1.z * dn, v1.w * dn);
        }
    }
}

// ---------------------------------------------------------------------------
// Fused layer-1 gather (int4 index loads, unroll 8, 4 accumulators) + bias +
// relu + GEMM2. 4 lanes per node; 64 nodes per 256-thread block. (R2-proven)
// ---------------------------------------------------------------------------
#define A1_NODES 64

__global__ __launch_bounds__(256) void agg1_gemm2_kernel(const int* __restrict__ rowptr,
                                                         const int* __restrict__ degA,
                                                         const int* __restrict__ csr_src,
                                                         const float* __restrict__ h1s,
                                                         const float* __restrict__ dinv,
                                                         const float* __restrict__ b1,
                                                         const float* __restrict__ W2,
                                                         float* __restrict__ h2s) {
    __shared__ float W2s[HID][8];
    __shared__ float t_lds[A1_NODES][HID + 1];
    const int tid = threadIdx.x;
    if (tid < HID * 8) {
        int j = tid >> 3, c = tid & 7;
        W2s[j][c] = (c < CLS) ? W2[j * CLS + c] : 0.f;
    }
    const int ln = tid >> 2;
    const int j4 = tid & 3;
    const int n = blockIdx.x * A1_NODES + ln;
    float dn = 0.f;
    if (n < N_NODES) {
        const int beg = rowptr[n];
        const int end = beg + degA[n];
        const float4* h4 = (const float4*)h1s;
        float4 a0 = make_float4(0.f, 0.f, 0.f, 0.f);
        float4 a1 = make_float4(0.f, 0.f, 0.f, 0.f);
        float4 a2 = make_float4(0.f, 0.f, 0.f, 0.f);
        float4 a3 = make_float4(0.f, 0.f, 0.f, 0.f);
        int k = beg;
        for (; k < end && (k & 3); k++) {            // peel to 16B alignment
            float4 v = h4[(long long)csr_src[k] * 4 + j4];
            ADD4(a0, v);
        }
        for (; k + 8 <= end; k += 8) {
            int4 s0 = *(const int4*)(csr_src + k);
            int4 s1 = *(const int4*)(csr_src + k + 4);
            float4 v0 = h4[(long long)s0.x * 4 + j4];
            float4 v1 = h4[(long long)s0.y * 4 + j4];
            float4 v2 = h4[(long long)s0.z * 4 + j4];
            float4 v3 = h4[(long long)s0.w * 4 + j4];
            float4 v4 = h4[(long long)s1.x * 4 + j4];
            float4 v5 = h4[(long long)s1.y * 4 + j4];
            float4 v6 = h4[(long long)s1.z * 4 + j4];
            float4 v7 = h4[(long long)s1.w * 4 + j4];
            ADD4(a0, v0); ADD4(a1, v1); ADD4(a2, v2); ADD4(a3, v3);
            ADD4(a0, v4); ADD4(a1, v5); ADD4(a2, v6); ADD4(a3, v7);
        }
        if (k + 4 <= end) {
            int4 s0 = *(const int4*)(csr_src + k);
            float4 v0 = h4[(long long)s0.x * 4 + j4];
            float4 v1 = h4[(long long)s0.y * 4 + j4];
            float4 v2 = h4[(long long)s0.z * 4 + j4];
            float4 v3 = h4[(long long)s0.w * 4 + j4];
            ADD4(a0, v0); ADD4(a1, v1); ADD4(a2, v2); ADD4(a3, v3);
            k += 4;
        }
        for (; k < end; k++) {
            float4 v = h4[(long long)csr_src[k] * 4 + j4];
            ADD4(a0, v);
        }
        dn = dinv[n];
        float4 self = h4[(long long)n * 4 + j4];
        float4 bb = ((const float4*)b1)[j4];
        float* tp = &t_lds[ln][j4 * 4];
        tp[0] = fmaxf(bb.x + dn * (a0.x + a1.x + a2.x + a3.x + self.x), 0.f);
        tp[1] = fmaxf(bb.y + dn * (a0.y + a1.y + a2.y + a3.y + self.y), 0.f);
        tp[2] = fmaxf(bb.z + dn * (a0.z + a1.z + a2.z + a3.z + self.z), 0.f);
        tp[3] = fmaxf(bb.w + dn * (a0.w + a1.w + a2.w + a3.w + self.w), 0.f);
    }
    __syncthreads();
    if (n < N_NODES) {
        float b0 = 0.f, c1 = 0.f;
#pragma unroll
        for (int j = 0; j < HID; j++) {
            float v = t_lds[ln][j];
            b0 += v * W2s[j][2 * j4];
            c1 += v * W2s[j][2 * j4 + 1];
        }
        h2s[(long long)n * 8 + 2 * j4]     = dn * b0;   // col7 = 0 via W2s pad
        h2s[(long long)n * 8 + 2 * j4 + 1] = dn * c1;
    }
}

// ---------------------------------------------------------------------------
// Layer-2 gather: 2 lanes/node, float4 gathers, int4 index loads, unroll 8.
// 128 nodes/block. (R2-proven)
// ---------------------------------------------------------------------------
#define A2_NODES 128

__global__ __launch_bounds__(256) void agg2_gather_kernel(const int* __restrict__ rowptr,
                                                          const int* __restrict__ degA,
                                                          const int* __restrict__ csr_src,
                                                          const float* __restrict__ h2s,
                                                          const float* __restrict__ dinv,
                                                          const float* __restrict__ b2,
                                                          float* __restrict__ out) {
    const int tid = threadIdx.x;
    const int ln = tid >> 1;
    const int half = tid & 1;
    const int n = blockIdx.x * A2_NODES + ln;
    if (n >= N_NODES) return;
    const int beg = rowptr[n];
    const int end = beg + degA[n];
    const float4* h4 = (const float4*)h2s;       // node row = 2 float4
    float4 a0 = make_float4(0.f, 0.f, 0.f, 0.f);
    float4 a1 = make_float4(0.f, 0.f, 0.f, 0.f);
    float4 a2 = make_float4(0.f, 0.f, 0.f, 0.f);
    float4 a3 = make_float4(0.f, 0.f, 0.f, 0.f);
    int k = beg;
    for (; k < end && (k & 3); k++) {
        float4 v = h4[(long long)csr_src[k] * 2 + half];
        ADD4(a0, v);
    }
    for (; k + 8 <= end; k += 8) {
        int4 s0 = *(const int4*)(csr_src + k);
        int4 s1 = *(const int4*)(csr_src + k + 4);
        float4 v0 = h4[(long long)s0.x * 2 + half];
        float4 v1 = h4[(long long)s0.y * 2 + half];
        float4 v2 = h4[(long long)s0.z * 2 + half];
        float4 v3 = h4[(long long)s0.w * 2 + half];
        float4 v4 = h4[(long long)s1.x * 2 + half];
        float4 v5 = h4[(long long)s1.y * 2 + half];
        float4 v6 = h4[(long long)s1.z * 2 + half];
        float4 v7 = h4[(long long)s1.w * 2 + half];
        ADD4(a0, v0); ADD4(a1, v1); ADD4(a2, v2); ADD4(a3, v3);
        ADD4(a0, v4); ADD4(a1, v5); ADD4(a2, v6); ADD4(a3, v7);
    }
    if (k + 4 <= end) {
        int4 s0 = *(const int4*)(csr_src + k);
        float4 v0 = h4[(long long)s0.x * 2 + half];
        float4 v1 = h4[(long long)s0.y * 2 + half];
        float4 v2 = h4[(long long)s0.z * 2 + half];
        float4 v3 = h4[(long long)s0.w * 2 + half];
        ADD4(a0, v0); ADD4(a1, v1); ADD4(a2, v2); ADD4(a3, v3);
        k += 4;
    }
    for (; k < end; k++) {
        float4 v = h4[(long long)csr_src[k] * 2 + half];
        ADD4(a0, v);
    }
    float dn = dinv[n];
    float4 self = h4[(long long)n * 2 + half];
    float tx = self.x + a0.x + a1.x + a2.x + a3.x;
    float ty = self.y + a0.y + a1.y + a2.y + a3.y;
    float tz = self.z + a0.z + a1.z + a2.z + a3.z;
    float tw = self.w + a0.w + a1.w + a2.w + a3.w;
    long long ob = (long long)n * CLS;
    if (half == 0) {
        out[ob + 0] = b2[0] + dn * tx;
        out[ob + 1] = b2[1] + dn * ty;
        out[ob + 2] = b2[2] + dn * tz;
        out[ob + 3] = b2[3] + dn * tw;
    } else {
        out[ob + 4] = b2[4] + dn * tx;
        out[ob + 5] = b2[5] + dn * ty;
        out[ob + 6] = b2[6] + dn * tz;
    }
}

// ---------------------------------------------------------------------------
extern "C" void kernel_launch(void* const* d_in, const int* in_sizes, int n_in,
                              void* d_out, int out_size, void* d_ws, size_t ws_size,
                              hipStream_t stream) {
    const float* x    = (const float*)d_in[0];
    const void*  eidx = d_in[1];
    const float* W1   = (const float*)d_in[2];
    const float* b1   = (const float*)d_in[3];
    const float* W2   = (const float*)d_in[4];
    const float* b2   = (const float*)d_in[5];
    float* out = (float*)d_out;
    const long long E = (long long)in_sizes[1] / 2;

    // workspace carve-up (256B aligned); total ~26 MB
    char* ws = (char*)d_ws;
    size_t off = 0;
    auto alloc = [&](size_t bytes) -> void* {
        void* p = ws + off;
        off = (off + bytes + 255) & ~(size_t)255;
        return p;
    };
    int*          cursor = (int*)alloc((size_t)NBK * 4);
    unsigned int* binned = (unsigned int*)alloc((size_t)NBK * BK_CAP * 4);  // -> csr_src
    int*          rowptr = (int*)alloc((size_t)N_NODES * 4);
    int*          degA   = (int*)alloc((size_t)N_NODES * 4);
    float*        dinv   = (float*)alloc((size_t)N_NODES * 4);
    float*        h1s    = (float*)alloc((size_t)N_NODES * HID * 4);
    float*        h2s    = (float*)alloc((size_t)N_NODES * 8 * 4);
    (void)ws_size;

    hipMemsetAsync(cursor, 0, (size_t)NBK * 4, stream);

    const int scBlocks = (int)((E + SB_TILE - 1) / SB_TILE);
    const int gmBlocks = (N_NODES + G1_ROWS - 1) / G1_ROWS;
    fat_kernel<<<scBlocks + gmBlocks, 256, 0, stream>>>(
        eidx, E, cursor, binned, x, W1, h1s, scBlocks);

    csr_build_kernel<<<NBK, 512, 0, stream>>>(cursor, binned, dinv, rowptr, degA, h1s);

    const int* csr_src = (const int*)binned;
    agg1_gemm2_kernel<<<(N_NODES + A1_NODES - 1) / A1_NODES, 256, 0, stream>>>(
        rowptr, degA, csr_src, h1s, dinv, b1, W2, h2s);

    agg2_gather_kernel<<<(N_NODES + A2_NODES - 1) / A2_NODES, 256, 0, stream>>>(
        rowptr, degA, csr_src, h2s, dinv, b2, out);
}

// Round 6
// 435.566 us; speedup vs baseline: 2.2494x; 1.0102x over previous
//
#include <hip/hip_runtime.h>

#define N_NODES 100000
#define F_IN 512
#define HID 16
#define CLS 7

#define BK_SHIFT 8
#define BK_NODES 256
#define NBK ((N_NODES + BK_NODES - 1) / BK_NODES)   // 391
#define BK_CAP 9216   // mean bucket = 8192 edges; cap = +11 sigma

#define SB_TILE 4096
#define SB_EPT 16          // edges per thread (256 threads)

#define G1_ROWS 128

#define ADD4(a, v) { (a).x += (v).x; (a).y += (v).y; (a).z += (v).z; (a).w += (v).w; }
#define FMA4(acc, sc, wv) { (acc).x += (sc)*(wv).x; (acc).y += (sc)*(wv).y; (acc).z += (sc)*(wv).z; (acc).w += (sc)*(wv).w; }

// ---------------------------------------------------------------------------
// FAT kernel: blocks [0, scBlocks) = edge multisplit into fixed-cap buckets;
// blocks [scBlocks, ...) = gemm1 x@W1 -> h1s UNSCALED (dinv in csr_build).
// R5 lesson: LDS union must stay small (occupancy is the scatter half's
// lifeline) -> NO xs staging tile; x is read direct-from-global (quad lanes
// broadcast the same 16B chunk; HBM bytes unchanged). W1 in LDS, broadcast
// reads, conflict-free. Union ~36KB -> 4 blocks/CU (16 waves).
// Edge packed to 4B: (dst&255)<<17 | src  (src < 2^17).
// ---------------------------------------------------------------------------
__global__ __launch_bounds__(256) void fat_kernel(const void* __restrict__ eidx,
                                                  long long E,
                                                  int* __restrict__ cursor,
                                                  unsigned int* __restrict__ binned,
                                                  const float* __restrict__ x,
                                                  const float* __restrict__ W1,
                                                  float* __restrict__ h1s,
                                                  int scBlocks) {
    __shared__ float Ws[F_IN * HID];             // 32 KB (gemm)
    __shared__ int hist[NBK];                    // 1.6 KB (scatter)
    __shared__ int gcur[NBK];                    // 1.6 KB (scatter)
    __shared__ unsigned int det;
    const int tid = threadIdx.x;

    if ((int)blockIdx.x < scBlocks) {
        // ----------------- scatter part -----------------
        const long long tileBeg = (long long)blockIdx.x * SB_TILE;
        long long remll = E - tileBeg;
        const int tcnt = (int)(remll < SB_TILE ? remll : SB_TILE);
        const bool evE = ((E & 1LL) == 0LL);

        for (int i = tid; i < NBK; i += 256) hist[i] = 0;
        if (tid == 0) det = 0u;
        __syncthreads();

        {   // local dtype detect on own tile (src half only -> in bounds)
            unsigned int myor = 0u;
            const unsigned long long* p64 = (const unsigned long long*)eidx;
            for (int i = tid; i < tcnt; i += 256)
                myor |= (unsigned int)(p64[tileBeg + i] >> 32);
            if (myor) atomicOr(&det, 1u);
        }
        __syncthreads();
        const int is64 = (det == 0u) ? 1 : 0;

        unsigned int vv[SB_EPT];
        int bb[SB_EPT];

#pragma unroll
        for (int j = 0; j < SB_EPT / 2; j++) {
            long long e = tileBeg + (long long)j * 512 + 2 * tid;
            int s0 = 0, d0 = 0, s1 = 0, d1 = 0;
            const bool ok0 = e < E, ok1 = (e + 1) < E;
            if (is64) {
                const long long* p = (const long long*)eidx;
                if (ok1 && evE) {
                    longlong2 sp = *(const longlong2*)(p + e);
                    longlong2 dp = *(const longlong2*)(p + E + e);
                    s0 = (int)sp.x; s1 = (int)sp.y; d0 = (int)dp.x; d1 = (int)dp.y;
                } else {
                    if (ok0) { s0 = (int)p[e];     d0 = (int)p[E + e]; }
                    if (ok1) { s1 = (int)p[e + 1]; d1 = (int)p[E + e + 1]; }
                }
            } else {
                const int* p = (const int*)eidx;
                if (ok1 && evE) {
                    int2 sp = *(const int2*)(p + e);
                    int2 dp = *(const int2*)(p + E + e);
                    s0 = sp.x; s1 = sp.y; d0 = dp.x; d1 = dp.y;
                } else {
                    if (ok0) { s0 = p[e];     d0 = p[E + e]; }
                    if (ok1) { s1 = p[e + 1]; d1 = p[E + e + 1]; }
                }
            }
            if (ok0) {
                int b = d0 >> BK_SHIFT;
                bb[2 * j] = b;
                vv[2 * j] = ((unsigned int)(d0 & (BK_NODES - 1)) << 17) | (unsigned int)s0;
                atomicAdd(&hist[b], 1);
            } else bb[2 * j] = -1;
            if (ok1) {
                int b = d1 >> BK_SHIFT;
                bb[2 * j + 1] = b;
                vv[2 * j + 1] = ((unsigned int)(d1 & (BK_NODES - 1)) << 17) | (unsigned int)s1;
                atomicAdd(&hist[b], 1);
            } else bb[2 * j + 1] = -1;
        }
        __syncthreads();
        for (int i = tid; i < NBK; i += 256)
            gcur[i] = hist[i] ? (i * BK_CAP + atomicAdd(&cursor[i], hist[i])) : 0;
        __syncthreads();
#pragma unroll
        for (int j = 0; j < SB_EPT; j++) {
            int b = bb[j];
            if (b >= 0) {
                int pos = atomicAdd(&gcur[b], 1);
                if (pos < (b + 1) * BK_CAP)          // overflow guard (unreachable)
                    binned[pos] = vv[j];
            }
        }
    } else {
        // ------------- gemm part: h1s = x @ W1 (unscaled, direct-x) -------------
        const int rowBase = ((int)blockIdx.x - scBlocks) * G1_ROWS;

#pragma unroll
        for (int it = 0; it < 8; it++) {
            int f = it * 256 + tid;
            ((float4*)Ws)[f] = ((const float4*)W1)[f];
        }
        __syncthreads();

        const int r  = tid >> 2;                 // 0..63
        const int j4 = tid & 3;
        int g0 = rowBase + r;
        int g1 = rowBase + 64 + r;
        int a0r = (g0 < N_NODES) ? g0 : N_NODES - 1;
        int a1r = (g1 < N_NODES) ? g1 : N_NODES - 1;
        const float4* xa4 = (const float4*)(x + (long long)a0r * F_IN);
        const float4* xb4 = (const float4*)(x + (long long)a1r * F_IN);
        const float4* Wf4 = (const float4*)Ws;

        float4 accA = make_float4(0.f, 0.f, 0.f, 0.f);
        float4 accB = make_float4(0.f, 0.f, 0.f, 0.f);

#pragma unroll 4
        for (int t = 0; t < F_IN / 4; t++) {     // 128 iters, 4 k-values each
            float4 xa = xa4[t];
            float4 xb = xb4[t];
            const float4* wp = Wf4 + t * 16 + j4;
            float4 w0 = wp[0];
            float4 w1 = wp[4];
            float4 w2 = wp[8];
            float4 w3 = wp[12];
            FMA4(accA, xa.x, w0); FMA4(accA, xa.y, w1);
            FMA4(accA, xa.z, w2); FMA4(accA, xa.w, w3);
            FMA4(accB, xb.x, w0); FMA4(accB, xb.y, w1);
            FMA4(accB, xb.z, w2); FMA4(accB, xb.w, w3);
        }
        if (g0 < N_NODES)
            ((float4*)(h1s + (long long)g0 * HID))[j4] = accA;
        if (g1 < N_NODES)
            ((float4*)(h1s + (long long)g1 * HID))[j4] = accB;
    }
}

// ---------------------------------------------------------------------------
// Per-bucket CSR finalize (R2-proven) + epilogue: scale this bucket's h1s
// rows by dinv (gemm wrote them unscaled; same multiply, bit-identical).
// ---------------------------------------------------------------------------
__global__ __launch_bounds__(512) void csr_build_kernel(const int* __restrict__ cursor,
                                                        unsigned int* __restrict__ binned,
                                                        float* __restrict__ dinv,
                                                        int* __restrict__ rowptr,
                                                        int* __restrict__ degA,
                                                        float* __restrict__ h1s) {
    __shared__ unsigned int stage[BK_CAP];       // 36 KB
    __shared__ int hist[BK_NODES];
    __shared__ int scanv[BK_NODES];
    __shared__ int curs[BK_NODES];
    const int tid = threadIdx.x;
    const int b = blockIdx.x;
    const int base = b * BK_CAP;
    int cnt = cursor[b];
    if (cnt > BK_CAP) cnt = BK_CAP;
    if (tid < BK_NODES) hist[tid] = 0;
    __syncthreads();
    const int cnt4 = cnt >> 2;
    for (int i = tid; i < cnt4; i += 512) {
        uint4 u = ((const uint4*)(binned + base))[i];
        ((uint4*)stage)[i] = u;
        atomicAdd(&hist[u.x >> 17], 1);
        atomicAdd(&hist[u.y >> 17], 1);
        atomicAdd(&hist[u.z >> 17], 1);
        atomicAdd(&hist[u.w >> 17], 1);
    }
    for (int i = (cnt4 << 2) + tid; i < cnt; i += 512) {
        unsigned int u = binned[base + i];
        stage[i] = u;
        atomicAdd(&hist[u >> 17], 1);
    }
    __syncthreads();
    if (tid < BK_NODES) scanv[tid] = hist[tid];
    __syncthreads();
    for (int off = 1; off < BK_NODES; off <<= 1) {
        int a = 0;
        if (tid < BK_NODES && tid >= off) a = scanv[tid - off];
        __syncthreads();
        if (tid < BK_NODES) scanv[tid] += a;
        __syncthreads();
    }
    if (tid < BK_NODES) {
        int e = scanv[tid] - hist[tid];
        curs[tid] = e;
        int g = b * BK_NODES + tid;
        if (g < N_NODES) {
            rowptr[g] = base + e;
            degA[g] = hist[tid];
            dinv[g] = rsqrtf((float)(hist[tid] + 1));   // +1 self-loop
        }
    }
    __syncthreads();
    for (int i = tid; i < cnt4; i += 512) {
        uint4 u = ((const uint4*)stage)[i];
        int p0 = atomicAdd(&curs[(int)(u.x >> 17)], 1); binned[base + p0] = u.x & 0x1FFFFu;
        int p1 = atomicAdd(&curs[(int)(u.y >> 17)], 1); binned[base + p1] = u.y & 0x1FFFFu;
        int p2 = atomicAdd(&curs[(int)(u.z >> 17)], 1); binned[base + p2] = u.z & 0x1FFFFu;
        int p3 = atomicAdd(&curs[(int)(u.w >> 17)], 1); binned[base + p3] = u.w & 0x1FFFFu;
    }
    for (int i = (cnt4 << 2) + tid; i < cnt; i += 512) {
        unsigned int u = stage[i];
        int p = atomicAdd(&curs[(int)(u >> 17)], 1);
        binned[base + p] = u & 0x1FFFFu;             // in place: binned becomes csr_src
    }
    // ---- h1 scale epilogue: 2 threads/node x 2 float4 (hist stable since scan)
    {
        const int ln = tid >> 1;                 // 0..255
        const int hf = tid & 1;
        const int g = b * BK_NODES + ln;
        if (g < N_NODES) {
            float dn = rsqrtf((float)(hist[ln] + 1));
            float4* hp = (float4*)(h1s + (long long)g * HID);
            float4 v0 = hp[hf * 2];
            float4 v1 = hp[hf * 2 + 1];
            hp[hf * 2]     = make_float4(v0.x * dn, v0.y * dn, v0.z * dn, v0.w * dn);
            hp[hf * 2 + 1] = make_float4(v1.x * dn, v1.y * dn, v1.z * dn, v1.w * dn);
        }
    }
}

// ---------------------------------------------------------------------------
// Fused layer-1 gather (int4 index loads, unroll 8, 4 accumulators) + bias +
// relu + GEMM2. 4 lanes per node; 64 nodes per 256-thread block. (R2-proven)
// ---------------------------------------------------------------------------
#define A1_NODES 64

__global__ __launch_bounds__(256) void agg1_gemm2_kernel(const int* __restrict__ rowptr,
                                                         const int* __restrict__ degA,
                                                         const int* __restrict__ csr_src,
                                                         const float* __restrict__ h1s,
                                                         const float* __restrict__ dinv,
                                                         const float* __restrict__ b1,
                                                         const float* __restrict__ W2,
                                                         float* __restrict__ h2s) {
    __shared__ float W2s[HID][8];
    __shared__ float t_lds[A1_NODES][HID + 1];
    const int tid = threadIdx.x;
    if (tid < HID * 8) {
        int j = tid >> 3, c = tid & 7;
        W2s[j][c] = (c < CLS) ? W2[j * CLS + c] : 0.f;
    }
    const int ln = tid >> 2;
    const int j4 = tid & 3;
    const int n = blockIdx.x * A1_NODES + ln;
    float dn = 0.f;
    if (n < N_NODES) {
        const int beg = rowptr[n];
        const int end = beg + degA[n];
        const float4* h4 = (const float4*)h1s;
        float4 a0 = make_float4(0.f, 0.f, 0.f, 0.f);
        float4 a1 = make_float4(0.f, 0.f, 0.f, 0.f);
        float4 a2 = make_float4(0.f, 0.f, 0.f, 0.f);
        float4 a3 = make_float4(0.f, 0.f, 0.f, 0.f);
        int k = beg;
        for (; k < end && (k & 3); k++) {            // peel to 16B alignment
            float4 v = h4[(long long)csr_src[k] * 4 + j4];
            ADD4(a0, v);
        }
        for (; k + 8 <= end; k += 8) {
            int4 s0 = *(const int4*)(csr_src + k);
            int4 s1 = *(const int4*)(csr_src + k + 4);
            float4 v0 = h4[(long long)s0.x * 4 + j4];
            float4 v1 = h4[(long long)s0.y * 4 + j4];
            float4 v2 = h4[(long long)s0.z * 4 + j4];
            float4 v3 = h4[(long long)s0.w * 4 + j4];
            float4 v4 = h4[(long long)s1.x * 4 + j4];
            float4 v5 = h4[(long long)s1.y * 4 + j4];
            float4 v6 = h4[(long long)s1.z * 4 + j4];
            float4 v7 = h4[(long long)s1.w * 4 + j4];
            ADD4(a0, v0); ADD4(a1, v1); ADD4(a2, v2); ADD4(a3, v3);
            ADD4(a0, v4); ADD4(a1, v5); ADD4(a2, v6); ADD4(a3, v7);
        }
        if (k + 4 <= end) {
            int4 s0 = *(const int4*)(csr_src + k);
            float4 v0 = h4[(long long)s0.x * 4 + j4];
            float4 v1 = h4[(long long)s0.y * 4 + j4];
            float4 v2 = h4[(long long)s0.z * 4 + j4];
            float4 v3 = h4[(long long)s0.w * 4 + j4];
            ADD4(a0, v0); ADD4(a1, v1); ADD4(a2, v2); ADD4(a3, v3);
            k += 4;
        }
        for (; k < end; k++) {
            float4 v = h4[(long long)csr_src[k] * 4 + j4];
            ADD4(a0, v);
        }
        dn = dinv[n];
        float4 self = h4[(long long)n * 4 + j4];
        float4 bb = ((const float4*)b1)[j4];
        float* tp = &t_lds[ln][j4 * 4];
        tp[0] = fmaxf(bb.x + dn * (a0.x + a1.x + a2.x + a3.x + self.x), 0.f);
        tp[1] = fmaxf(bb.y + dn * (a0.y + a1.y + a2.y + a3.y + self.y), 0.f);
        tp[2] = fmaxf(bb.z + dn * (a0.z + a1.z + a2.z + a3.z + self.z), 0.f);
        tp[3] = fmaxf(bb.w + dn * (a0.w + a1.w + a2.w + a3.w + self.w), 0.f);
    }
    __syncthreads();
    if (n < N_NODES) {
        float b0 = 0.f, c1 = 0.f;
#pragma unroll
        for (int j = 0; j < HID; j++) {
            float v = t_lds[ln][j];
            b0 += v * W2s[j][2 * j4];
            c1 += v * W2s[j][2 * j4 + 1];
        }
        h2s[(long long)n * 8 + 2 * j4]     = dn * b0;   // col7 = 0 via W2s pad
        h2s[(long long)n * 8 + 2 * j4 + 1] = dn * c1;
    }
}

// ---------------------------------------------------------------------------
// Layer-2 gather: 2 lanes/node, float4 gathers, int4 index loads, unroll 8.
// 128 nodes/block. (R2-proven)
// ---------------------------------------------------------------------------
#define A2_NODES 128

__global__ __launch_bounds__(256) void agg2_gather_kernel(const int* __restrict__ rowptr,
                                                          const int* __restrict__ degA,
                                                          const int* __restrict__ csr_src,
                                                          const float* __restrict__ h2s,
                                                          const float* __restrict__ dinv,
                                                          const float* __restrict__ b2,
                                                          float* __restrict__ out) {
    const int tid = threadIdx.x;
    const int ln = tid >> 1;
    const int half = tid & 1;
    const int n = blockIdx.x * A2_NODES + ln;
    if (n >= N_NODES) return;
    const int beg = rowptr[n];
    const int end = beg + degA[n];
    const float4* h4 = (const float4*)h2s;       // node row = 2 float4
    float4 a0 = make_float4(0.f, 0.f, 0.f, 0.f);
    float4 a1 = make_float4(0.f, 0.f, 0.f, 0.f);
    float4 a2 = make_float4(0.f, 0.f, 0.f, 0.f);
    float4 a3 = make_float4(0.f, 0.f, 0.f, 0.f);
    int k = beg;
    for (; k < end && (k & 3); k++) {
        float4 v = h4[(long long)csr_src[k] * 2 + half];
        ADD4(a0, v);
    }
    for (; k + 8 <= end; k += 8) {
        int4 s0 = *(const int4*)(csr_src + k);
        int4 s1 = *(const int4*)(csr_src + k + 4);
        float4 v0 = h4[(long long)s0.x * 2 + half];
        float4 v1 = h4[(long long)s0.y * 2 + half];
        float4 v2 = h4[(long long)s0.z * 2 + half];
        float4 v3 = h4[(long long)s0.w * 2 + half];
        float4 v4 = h4[(long long)s1.x * 2 + half];
        float4 v5 = h4[(long long)s1.y * 2 + half];
        float4 v6 = h4[(long long)s1.z * 2 + half];
        float4 v7 = h4[(long long)s1.w * 2 + half];
        ADD4(a0, v0); ADD4(a1, v1); ADD4(a2, v2); ADD4(a3, v3);
        ADD4(a0, v4); ADD4(a1, v5); ADD4(a2, v6); ADD4(a3, v7);
    }
    if (k + 4 <= end) {
        int4 s0 = *(const int4*)(csr_src + k);
        float4 v0 = h4[(long long)s0.x * 2 + half];
        float4 v1 = h4[(long long)s0.y * 2 + half];
        float4 v2 = h4[(long long)s0.z * 2 + half];
        float4 v3 = h4[(long long)s0.w * 2 + half];
        ADD4(a0, v0); ADD4(a1, v1); ADD4(a2, v2); ADD4(a3, v3);
        k += 4;
    }
    for (; k < end; k++) {
        float4 v = h4[(long long)csr_src[k] * 2 + half];
        ADD4(a0, v);
    }
    float dn = dinv[n];
    float4 self = h4[(long long)n * 2 + half];
    float tx = self.x + a0.x + a1.x + a2.x + a3.x;
    float ty = self.y + a0.y + a1.y + a2.y + a3.y;
    float tz = self.z + a0.z + a1.z + a2.z + a3.z;
    float tw = self.w + a0.w + a1.w + a2.w + a3.w;
    long long ob = (long long)n * CLS;
    if (half == 0) {
        out[ob + 0] = b2[0] + dn * tx;
        out[ob + 1] = b2[1] + dn * ty;
        out[ob + 2] = b2[2] + dn * tz;
        out[ob + 3] = b2[3] + dn * tw;
    } else {
        out[ob + 4] = b2[4] + dn * tx;
        out[ob + 5] = b2[5] + dn * ty;
        out[ob + 6] = b2[6] + dn * tz;
    }
}

// ---------------------------------------------------------------------------
extern "C" void kernel_launch(void* const* d_in, const int* in_sizes, int n_in,
                              void* d_out, int out_size, void* d_ws, size_t ws_size,
                              hipStream_t stream) {
    const float* x    = (const float*)d_in[0];
    const void*  eidx = d_in[1];
    const float* W1   = (const float*)d_in[2];
    const float* b1   = (const float*)d_in[3];
    const float* W2   = (const float*)d_in[4];
    const float* b2   = (const float*)d_in[5];
    float* out = (float*)d_out;
    const long long E = (long long)in_sizes[1] / 2;

    // workspace carve-up (256B aligned); total ~26 MB
    char* ws = (char*)d_ws;
    size_t off = 0;
    auto alloc = [&](size_t bytes) -> void* {
        void* p = ws + off;
        off = (off + bytes + 255) & ~(size_t)255;
        return p;
    };
    int*          cursor = (int*)alloc((size_t)NBK * 4);
    unsigned int* binned = (unsigned int*)alloc((size_t)NBK * BK_CAP * 4);  // -> csr_src
    int*          rowptr = (int*)alloc((size_t)N_NODES * 4);
    int*          degA   = (int*)alloc((size_t)N_NODES * 4);
    float*        dinv   = (float*)alloc((size_t)N_NODES * 4);
    float*        h1s    = (float*)alloc((size_t)N_NODES * HID * 4);
    float*        h2s    = (float*)alloc((size_t)N_NODES * 8 * 4);
    (void)ws_size;

    hipMemsetAsync(cursor, 0, (size_t)NBK * 4, stream);

    const int scBlocks = (int)((E + SB_TILE - 1) / SB_TILE);
    const int gmBlocks = (N_NODES + G1_ROWS - 1) / G1_ROWS;
    fat_kernel<<<scBlocks + gmBlocks, 256, 0, stream>>>(
        eidx, E, cursor, binned, x, W1, h1s, scBlocks);

    csr_build_kernel<<<NBK, 512, 0, stream>>>(cursor, binned, dinv, rowptr, degA, h1s);

    const int* csr_src = (const int*)binned;
    agg1_gemm2_kernel<<<(N_NODES + A1_NODES - 1) / A1_NODES, 256, 0, stream>>>(
        rowptr, degA, csr_src, h1s, dinv, b1, W2, h2s);

    agg2_gather_kernel<<<(N_NODES + A2_NODES - 1) / A2_NODES, 256, 0, stream>>>(
        rowptr, degA, csr_src, h2s, dinv, b2, out);
}